// Round 1
// 199.254 us; speedup vs baseline: 1.0156x; 1.0156x over previous
//
#include <hip/hip_runtime.h>

#define D      1024
#define SEQ    128
#define BATCH  256
#define DQ     256
#define TEXTC  768

typedef float f32x4 __attribute__((ext_vector_type(4)));
typedef float f32x2 __attribute__((ext_vector_type(2)));

// ---------------------------------------------------------------------------
// Kernel 1: split-K partial GEMM, fused activation build.
//   part[z][m][n] = sum_{k in [z*256,z*256+256)} act[m][k] * W[k][n]  (+bias z=0)
// act[m][k<256]  = relu(sv@W1+b1) computed in-register during A staging (z=0)
// act[m][k>=256] = page_captions[m][k-256]                            (z=1..3)
// W = [style_w2 rows 0..255 ; text_w rows 256..1023].
// Grid (8,16,4) = 512 blocks (2/CU, 8 waves/CU), 32x64 tile, 2x4 micro-tile.
// kc-step = 32 (was 16): halves the __syncthreads count; all 256 threads
// stage A (13.3 KB LDS, still 2 blocks/CU).
// ---------------------------------------------------------------------------
__global__ __launch_bounds__(256) void gemm_fused(
    const float* __restrict__ style_vectors,  // [256][5]
    const float* __restrict__ page_captions,  // [256][768]
    const float* __restrict__ style_w1,       // [5][256]
    const float* __restrict__ style_b1,       // [256]
    const float* __restrict__ style_w2,       // [256][1024]
    const float* __restrict__ style_b2,       // [1024]
    const float* __restrict__ text_w,         // [768][1024]
    const float* __restrict__ text_b,         // [1024]
    float* __restrict__ part)                 // [4][256][1024]
{
    __shared__ float As[32][36];   // [k][m], +pad
    __shared__ float Bs[32][68];   // [k][n], +pad (16B-aligned rows)

    const int m0  = blockIdx.x * 32;
    const int n0  = blockIdx.y * 64;
    const int z   = blockIdx.z;            // K chunk: [z*256, z*256+256)
    const int tid = threadIdx.x;
    const int tm  = tid >> 4;              // 0..15 -> rows m0+tm*2 .. +1
    const int tn  = tid & 15;              // 0..15 -> cols n0+tn*4 .. +3

    // A staging (all 256 threads): thread covers (m0+am, kc+ak..kc+ak+3)
    const int am = tid >> 3;               // 0..31
    const int ak = (tid & 7) * 4;          // 0,4,..,28

    float sv[5];
    if (z == 0) {
#pragma unroll
        for (int j = 0; j < 5; ++j) sv[j] = style_vectors[(m0 + am) * 5 + j];
    }

    float acc[2][4] = {};

    for (int kc = 0; kc < 256; kc += 32) {
        // ---- A tile: [32 k][32 m] ----
        if (z == 0) {
            int k = kc + ak;               // style region, k < 256
#pragma unroll
            for (int r = 0; r < 4; ++r) {
                float h = style_b1[k + r];
#pragma unroll
                for (int j = 0; j < 5; ++j)
                    h = fmaf(sv[j], style_w1[j * DQ + k + r], h);
                As[ak + r][am] = fmaxf(h, 0.0f);
            }
        } else {
            float4 av = *(const float4*)
                &page_captions[(m0 + am) * TEXTC + (z * 256 - DQ) + kc + ak];
            As[ak + 0][am] = av.x;
            As[ak + 1][am] = av.y;
            As[ak + 2][am] = av.z;
            As[ak + 3][am] = av.w;
        }
        // ---- B tile: [32 k][64 n], 2 float4 per thread ----
        {
            int kk = tid >> 4;             // 0..15
            int nq = (tid & 15) * 4;       // 0..60
#pragma unroll
            for (int h = 0; h < 2; ++h) {
                int kl   = kk + 16 * h;    // 0..31 tile-local
                int krow = z * 256 + kc + kl;
                const float* Wrow = (z == 0) ? &style_w2[krow * D]
                                             : &text_w[(krow - DQ) * D];
                *(f32x4*)&Bs[kl][nq] = *(const f32x4*)&Wrow[n0 + nq];
            }
        }
        __syncthreads();

#pragma unroll
        for (int kk = 0; kk < 32; ++kk) {
            f32x2 a2 = *(const f32x2*)&As[kk][tm * 2];
            f32x4 b4 = *(const f32x4*)&Bs[kk][tn * 4];
#pragma unroll
            for (int ii = 0; ii < 2; ++ii)
#pragma unroll
                for (int jj = 0; jj < 4; ++jj)
                    acc[ii][jj] = fmaf(a2[ii], b4[jj], acc[ii][jj]);
        }
        __syncthreads();
    }

    float* dst = part + (size_t)z * BATCH * D;
    const int n = n0 + tn * 4;
#pragma unroll
    for (int ii = 0; ii < 2; ++ii) {
        int m = m0 + tm * 2 + ii;
        f32x4 v = {acc[ii][0], acc[ii][1], acc[ii][2], acc[ii][3]};
        if (z == 0) {
            v[0] += style_b2[n + 0] + text_b[n + 0];
            v[1] += style_b2[n + 1] + text_b[n + 1];
            v[2] += style_b2[n + 2] + text_b[n + 2];
            v[3] += style_b2[n + 3] + text_b[n + 3];
        }
        *(f32x4*)&dst[m * D + n] = v;      // plain store: keep part L2-resident
    }
}

// ---------------------------------------------------------------------------
// Kernel 2 (was 3): out[b,s,:] = type_emb[et] + pos_emb[ei] + final_pos_emb[s]
//                   + (et==1 ? sum_z part[z][b] : 0);  mask = (et==0)
// Reduce kernel fused away: the 4 split-K partials are summed in-flight for
// et==1 rows (part is 4 MB -> L2-resident; scatter stays write-bound).
// 4 rows per block, one 64-lane wave per row, 4 independent float4
// nontemporal stores per thread; et==1 branch is wave-uniform.
// ---------------------------------------------------------------------------
__global__ __launch_bounds__(256) void scatter_kernel(
    const int* __restrict__ types,           // [256][128]
    const int* __restrict__ indices,         // [256][128]
    const float* __restrict__ type_emb,      // [5][1024]
    const float* __restrict__ pos_emb,       // [128][1024]
    const float* __restrict__ final_pos_emb, // [128][1024]
    const float* __restrict__ part,          // [4][256][1024]
    float* __restrict__ out_emb,             // [256][128][1024]
    float* __restrict__ out_mask)            // [256][128]
{
    const int tid  = threadIdx.x;
    const int wave = tid >> 6;
    const int lane = tid & 63;
    const int bs   = blockIdx.x * 4 + wave;   // 0..32767
    const int b    = bs >> 7;
    const int s    = bs & 127;
    const int et   = types[bs];
    const int ei   = indices[bs];

    const f32x4* te = (const f32x4*)&type_emb[et * D];
    const f32x4* pe = (const f32x4*)&pos_emb[ei * D];
    const f32x4* fe = (const f32x4*)&final_pos_emb[s * D];
    f32x4* dst = (f32x4*)out_emb + (size_t)bs * 256;

    if (et == 1) {
        const int Q = BATCH * D / 4;                       // 65536 f32x4 / z-plane
        const f32x4* pp = (const f32x4*)part + b * 256;    // row b of z=0
#pragma unroll
        for (int j = 0; j < 4; ++j) {
            int idx = lane + 64 * j;
            f32x4 v = te[idx] + pe[idx] + fe[idx]
                    + pp[idx] + pp[idx + Q] + pp[idx + 2 * Q] + pp[idx + 3 * Q];
            __builtin_nontemporal_store(v, &dst[idx]);
        }
    } else {
#pragma unroll
        for (int j = 0; j < 4; ++j) {
            int idx = lane + 64 * j;
            f32x4 v = te[idx] + pe[idx] + fe[idx];
            __builtin_nontemporal_store(v, &dst[idx]);
        }
    }

    if (lane == 0)
        out_mask[bs] = (et == 0) ? 1.0f : 0.0f;
}

// ---------------------------------------------------------------------------
extern "C" void kernel_launch(void* const* d_in, const int* in_sizes, int n_in,
                              void* d_out, int out_size, void* d_ws, size_t ws_size,
                              hipStream_t stream) {
    const int*   element_types   = (const int*)  d_in[0];
    const int*   element_indices = (const int*)  d_in[1];
    const float* style_vectors   = (const float*)d_in[2];
    const float* page_captions   = (const float*)d_in[3];
    const float* type_emb        = (const float*)d_in[4];
    const float* pos_emb         = (const float*)d_in[5];
    const float* style_w1        = (const float*)d_in[6];
    const float* style_b1        = (const float*)d_in[7];
    const float* style_w2        = (const float*)d_in[8];
    const float* style_b2        = (const float*)d_in[9];
    const float* text_w          = (const float*)d_in[10];
    const float* text_b          = (const float*)d_in[11];
    const float* final_pos_emb   = (const float*)d_in[12];

    float* part = (float*)d_ws;                           // 4*256*1024 = 4 MB

    float* out_emb  = (float*)d_out;                      // 256*128*1024
    float* out_mask = (float*)d_out + BATCH * SEQ * D;    // 256*128

    // 1) split-K GEMM, 512 blocks (2 blocks/CU)
    gemm_fused<<<dim3(BATCH / 32, D / 64, 4), 256, 0, stream>>>(
        style_vectors, page_captions, style_w1, style_b1,
        style_w2, style_b2, text_w, text_b, part);

    // 2) big masked gather-add write, partial-sum fused (4 rows/block)
    scatter_kernel<<<BATCH * SEQ / 4, 256, 0, stream>>>(
        element_types, element_indices, type_emb, pos_emb, final_pos_emb,
        part, out_emb, out_mask);
}

// Round 2
// 191.998 us; speedup vs baseline: 1.0540x; 1.0378x over previous
//
#include <hip/hip_runtime.h>

#define D      1024
#define SEQ    128
#define BATCH  256
#define DQ     256
#define TEXTC  768

typedef float f32x4 __attribute__((ext_vector_type(4)));

// ---------------------------------------------------------------------------
// Kernel 1 — wave-specialized: GEMM hidden under the output write stream.
//   waves 0-1: one wave-private 16x64 (K=256) partial GEMM tile each
//              -> part[z][m][n]. 512 blocks x 2 = 1024 wave-tiles
//              = 16 m-tiles x 16 n-tiles x 4 z-chunks.
//              LDS tiles are wave-private => NO __syncthreads anywhere
//              (wave64 lockstep + compiler lgkmcnt = wave-synchronous).
//   waves 2-3: scatter rows [bid*64+(w-2)*32, +32): for et!=1 rows write
//              te+pe+fe (107 MB, 80% of output) + mask for ALL rows.
//              et==1 rows are left for kernel 2 (they need the full GEMM).
// Timeline per CU: GEMM waves done ~5us, write waves saturate HBM ~18us.
// ---------------------------------------------------------------------------
__global__ __launch_bounds__(256) void k1_gemm_scatter(
    const int* __restrict__ types,           // [256][128]
    const int* __restrict__ indices,         // [256][128]
    const float* __restrict__ type_emb,      // [5][1024]
    const float* __restrict__ pos_emb,       // [128][1024]
    const float* __restrict__ final_pos_emb, // [128][1024]
    const float* __restrict__ style_vectors, // [256][5]
    const float* __restrict__ page_captions, // [256][768]
    const float* __restrict__ style_w1,      // [5][256]
    const float* __restrict__ style_b1,      // [256]
    const float* __restrict__ style_w2,      // [256][1024]
    const float* __restrict__ style_b2,      // [1024]
    const float* __restrict__ text_w,        // [768][1024]
    const float* __restrict__ text_b,        // [1024]
    float* __restrict__ part,                // [4][256][1024]
    float* __restrict__ out_emb,             // [256][128][1024]
    float* __restrict__ out_mask)            // [256][128]
{
    __shared__ float As[2][32][20];   // [wave][k][m], pad 20 (16B-aligned rows)
    __shared__ float Bs[2][32][68];   // [wave][k][n], pad 68 (16B-aligned rows)

    const int tid  = threadIdx.x;
    const int wave = tid >> 6;
    const int lane = tid & 63;
    const int bid  = blockIdx.x;

    if (wave < 2) {
        // ------------------- GEMM half (waves 0,1) -------------------
        const int w   = bid * 2 + wave;       // 0..1023
        const int z   = w >> 8;               // K chunk [z*256, z*256+256)
        const int rem = w & 255;
        const int m0  = (rem & 15) << 4;      // 16-row tile
        const int n0  = (rem >> 4) << 6;      // 64-col tile

        float (*A)[20] = As[wave];
        float (*B)[68] = Bs[wave];

        const int sm  = lane >> 2;            // staging row 0..15
        const int sk  = (lane & 3) << 3;      // staging k0: 0,8,16,24
        const int tm4 = (lane >> 4) << 2;     // compute rows tm4..tm4+3
        const int tn4 = (lane & 15) << 2;     // compute cols tn4..tn4+3
        const int bkl = lane >> 4;            // B staging k row base

        float sv[5];
        if (z == 0) {
#pragma unroll
            for (int j = 0; j < 5; ++j) sv[j] = style_vectors[(m0 + sm) * 5 + j];
        }

        f32x4 acc[4] = {};                    // acc[r] = row tm4+r, 4 cols

        for (int kc = 0; kc < 256; kc += 32) {
            // ---- A tile [32k][16m]: relu(sv@W1+b1) (z=0) or captions ----
            if (z == 0) {
                const int kg = kc + sk;
                f32x4 h0 = *(const f32x4*)&style_b1[kg];
                f32x4 h1 = *(const f32x4*)&style_b1[kg + 4];
#pragma unroll
                for (int j = 0; j < 5; ++j) {
                    h0 += sv[j] * *(const f32x4*)&style_w1[j * DQ + kg];
                    h1 += sv[j] * *(const f32x4*)&style_w1[j * DQ + kg + 4];
                }
#pragma unroll
                for (int r = 0; r < 4; ++r) {
                    A[sk + r][sm]     = fmaxf(h0[r], 0.0f);
                    A[sk + 4 + r][sm] = fmaxf(h1[r], 0.0f);
                }
            } else {
                const float* cap =
                    &page_captions[(m0 + sm) * TEXTC + (z - 1) * 256 + kc + sk];
                f32x4 a0 = *(const f32x4*)cap;
                f32x4 a1 = *(const f32x4*)(cap + 4);
#pragma unroll
                for (int r = 0; r < 4; ++r) {
                    A[sk + r][sm]     = a0[r];
                    A[sk + 4 + r][sm] = a1[r];
                }
            }
            // ---- B tile [32k][64n] ----
#pragma unroll
            for (int h = 0; h < 8; ++h) {
                int kl   = bkl + (h << 2);
                int krow = (z << 8) + kc + kl;
                const float* Wrow = (z == 0) ? &style_w2[krow * D]
                                             : &text_w[(krow - DQ) * D];
                *(f32x4*)&B[kl][tn4] = *(const f32x4*)&Wrow[n0 + tn4];
            }
            __builtin_amdgcn_wave_barrier();   // pin stage->compute order
            // ---- 16 FMA per kk, wave-private, no block barrier ----
#pragma unroll
            for (int kk = 0; kk < 32; ++kk) {
                f32x4 a4 = *(const f32x4*)&A[kk][tm4];
                f32x4 b4 = *(const f32x4*)&B[kk][tn4];
#pragma unroll
                for (int r = 0; r < 4; ++r)
                    acc[r] += a4[r] * b4;
            }
            __builtin_amdgcn_wave_barrier();   // pin compute->next-stage order
        }

        f32x4 bias = {};
        if (z == 0)
            bias = *(const f32x4*)&style_b2[n0 + tn4]
                 + *(const f32x4*)&text_b[n0 + tn4];
#pragma unroll
        for (int r = 0; r < 4; ++r) {
            int m = m0 + tm4 + r;
            f32x4 v = acc[r];
            if (z == 0) v += bias;
            *(f32x4*)&part[((size_t)z * BATCH + m) * D + n0 + tn4] = v;
        }
    } else {
        // ------------------- scatter half (waves 2,3) -------------------
        const int r0 = bid * 64 + ((wave - 2) << 5);   // 32 rows per wave
        const int lr = lane & 31;
        const int myet = types[r0 + lr];
        const int myei = indices[r0 + lr];
        if (lane < 32)
            out_mask[r0 + lane] = (myet == 0) ? 1.0f : 0.0f;

#pragma unroll 4
        for (int r = 0; r < 32; ++r) {
            const int et = __shfl(myet, r);    // wave-uniform broadcast
            const int ei = __shfl(myei, r);
            if (et == 1) continue;             // kernel 2's job
            const int bs = r0 + r;
            const int s  = bs & 127;
            const f32x4* te = (const f32x4*)&type_emb[et * D];
            const f32x4* pe = (const f32x4*)&pos_emb[ei * D];
            const f32x4* fe = (const f32x4*)&final_pos_emb[s * D];
            f32x4* dst = (f32x4*)out_emb + (size_t)bs * 256;
#pragma unroll
            for (int j = 0; j < 4; ++j) {
                int idx = lane + (j << 6);
                f32x4 v = te[idx] + pe[idx] + fe[idx];
                __builtin_nontemporal_store(v, &dst[idx]);
            }
        }
    }
}

// ---------------------------------------------------------------------------
// Kernel 2 — et==1 rows only. comb = sum_z part[z][b] staged ONCE per block
// in LDS (part reads: 105 MB -> 8 MB), then stream the remaining ~27 MB.
// Grid 512 = (b, s-half); 4 waves x 16 rows, wave-per-row writes.
// ---------------------------------------------------------------------------
__global__ __launch_bounds__(256) void k2_comb_scatter(
    const int* __restrict__ types,
    const int* __restrict__ indices,
    const float* __restrict__ type_emb,
    const float* __restrict__ pos_emb,
    const float* __restrict__ final_pos_emb,
    const float* __restrict__ part,          // [4][256][1024]
    float* __restrict__ out_emb)
{
    __shared__ f32x4 comb[256];              // one 1024-float row

    const int tid = threadIdx.x;
    const int bid = blockIdx.x;
    const int b   = bid >> 1;
    const int sh  = (bid & 1) << 6;

    {
        const int Q = BATCH * D / 4;         // f32x4 per z-plane
        const f32x4* p = (const f32x4*)part + b * 256 + tid;
        comb[tid] = p[0] + p[Q] + p[2 * Q] + p[3 * Q];
    }
    __syncthreads();

    const int wave = tid >> 6;
    const int lane = tid & 63;
    const int s0   = sh + (wave << 4);       // 16 rows per wave
    const int bs0  = (b << 7) + s0;
    const int myet = types[bs0 + (lane & 15)];
    const int myei = indices[bs0 + (lane & 15)];

#pragma unroll 4
    for (int r = 0; r < 16; ++r) {
        const int et = __shfl(myet, r);
        const int ei = __shfl(myei, r);
        if (et != 1) continue;
        const int bs = bs0 + r;
        const int s  = s0 + r;
        const f32x4* te = (const f32x4*)&type_emb[et * D];   // et==1
        const f32x4* pe = (const f32x4*)&pos_emb[ei * D];
        const f32x4* fe = (const f32x4*)&final_pos_emb[s * D];
        f32x4* dst = (f32x4*)out_emb + (size_t)bs * 256;
#pragma unroll
        for (int j = 0; j < 4; ++j) {
            int idx = lane + (j << 6);
            f32x4 v = te[idx] + pe[idx] + fe[idx] + comb[idx];
            __builtin_nontemporal_store(v, &dst[idx]);
        }
    }
}

// ---------------------------------------------------------------------------
extern "C" void kernel_launch(void* const* d_in, const int* in_sizes, int n_in,
                              void* d_out, int out_size, void* d_ws, size_t ws_size,
                              hipStream_t stream) {
    const int*   element_types   = (const int*)  d_in[0];
    const int*   element_indices = (const int*)  d_in[1];
    const float* style_vectors   = (const float*)d_in[2];
    const float* page_captions   = (const float*)d_in[3];
    const float* type_emb        = (const float*)d_in[4];
    const float* pos_emb         = (const float*)d_in[5];
    const float* style_w1        = (const float*)d_in[6];
    const float* style_b1        = (const float*)d_in[7];
    const float* style_w2        = (const float*)d_in[8];
    const float* style_b2        = (const float*)d_in[9];
    const float* text_w          = (const float*)d_in[10];
    const float* text_b          = (const float*)d_in[11];
    const float* final_pos_emb   = (const float*)d_in[12];

    float* part = (float*)d_ws;                           // 4*256*1024 = 4 MB

    float* out_emb  = (float*)d_out;                      // 256*128*1024
    float* out_mask = (float*)d_out + BATCH * SEQ * D;    // 256*128

    // 1) GEMM (hidden) + 80% of output stream + mask
    k1_gemm_scatter<<<512, 256, 0, stream>>>(
        element_types, element_indices, type_emb, pos_emb, final_pos_emb,
        style_vectors, page_captions, style_w1, style_b1,
        style_w2, style_b2, text_w, text_b,
        part, out_emb, out_mask);

    // 2) et==1 rows: comb staged in LDS, remaining ~20% of output stream
    k2_comb_scatter<<<512, 256, 0, stream>>>(
        element_types, element_indices, type_emb, pos_emb, final_pos_emb,
        part, out_emb);
}